// Round 5
// baseline (689.567 us; speedup 1.0000x reference)
//
#include <hip/hip_runtime.h>

#define N_TOK   524288
#define KC      256
#define D       32
#define EPSF    1e-6f
#define GPW     16                 // tokens per wave-group
#define NGRP    (N_TOK / GPW)      // 32768
#define NBLK    1024
#define BLKT    256
#define DELTA   0.008f             // candidate margin >> 2x bf16-cvt score error (~1.7e-3)
#define FINF    3.4e38f
#define WS_HIST_OFF 64             // floats; ws[0] = steal counter

typedef __attribute__((ext_vector_type(8))) short bf16x8;
typedef __attribute__((ext_vector_type(4))) float f32x4;

__device__ inline short f32_bf16_rne(float f) {
    unsigned u = __float_as_uint(f);
    u = (u + 0x7fffu + ((u >> 16) & 1u)) >> 16;
    return (short)u;
}

// ---------------- main kernel: MFMA approx filter + exact f32 rescore ----------------
__global__ __launch_bounds__(BLKT, 4) void vq_main(
    const float* __restrict__ x, const float* __restrict__ cb,
    float* __restrict__ out_rot, float* __restrict__ out_idx,
    float* __restrict__ ws, float* __restrict__ out_cnt, int use_ws)
{
    // cb bf16, row stride 40 shorts (80 B): B-frag reads 2-way bank aliased = free
    __shared__ short cbb[KC * 40];
    __shared__ float c2s[KC];      // ||c||^2, numpy pairwise order (exact)
    __shared__ float hist[KC];

    const int tid  = threadIdx.x;
    const int lane = tid & 63;
    const int wv   = tid >> 6;
    const int m    = lane & 15;    // A-frag row / B-frag col / C col
    const int q    = lane >> 4;    // k-quad / C row-quad

    // ---- init: c2 (numpy pairwise, exact) + bf16 codebook ----
    {
        const float4* cb4 = (const float4*)(cb + (size_t)tid * D);
        float4 r[8];
#pragma unroll
        for (int j = 0; j < 8; j++) r[j] = cb4[j];
        {
#pragma clang fp contract(off)
            float t[32];
#pragma unroll
            for (int j = 0; j < 8; j++) {
                t[4 * j + 0] = r[j].x * r[j].x;
                t[4 * j + 1] = r[j].y * r[j].y;
                t[4 * j + 2] = r[j].z * r[j].z;
                t[4 * j + 3] = r[j].w * r[j].w;
            }
            float pr[8];
#pragma unroll
            for (int j = 0; j < 8; j++)
                pr[j] = ((t[j] + t[j + 8]) + t[j + 16]) + t[j + 24];
            c2s[tid] = ((pr[0] + pr[1]) + (pr[2] + pr[3])) + ((pr[4] + pr[5]) + (pr[6] + pr[7]));
        }
#pragma unroll
        for (int j = 0; j < 8; j++) {
            cbb[tid * 40 + 4 * j + 0] = f32_bf16_rne(r[j].x);
            cbb[tid * 40 + 4 * j + 1] = f32_bf16_rne(r[j].y);
            cbb[tid * 40 + 4 * j + 2] = f32_bf16_rne(r[j].z);
            cbb[tid * 40 + 4 * j + 3] = f32_bf16_rne(r[j].w);
        }
        hist[tid] = 0.f;
    }
    __syncthreads();

    uint* cnt = (uint*)ws;

    for (int it = 0;; it++) {
        int g;
        if (use_ws) {
            int v = 0;
            if (lane == 0) v = (int)atomicAdd(cnt, 1u);
            g = __shfl(v, 0, 64);
        } else {
            g = (blockIdx.x * 4 + wv) + it * (int)gridDim.x * 4;
        }
        if (g >= NGRP) break;
        const int t0 = g * GPW;

        // ---- load x fragment: token t0+m, dims q*8..q*8+7 (wave covers 2 KB dense) ----
        float xr[8];
        {
            const float4* xp = (const float4*)(x + (size_t)(t0 + m) * D + q * 8);
            float4 a = xp[0], b = xp[1];
            xr[0] = a.x; xr[1] = a.y; xr[2] = a.z; xr[3] = a.w;
            xr[4] = b.x; xr[5] = b.y; xr[6] = b.z; xr[7] = b.w;
        }
        bf16x8 af;
#pragma unroll
        for (int j = 0; j < 8; j++) af[j] = f32_bf16_rne(xr[j]);

        // ---- x2 exact numpy-pairwise via shuffles: ((q0+q1)+q2)+q3 per j ----
        float x2b[4];
        {
#pragma clang fp contract(off)
            float pr[8];
#pragma unroll
            for (int j = 0; j < 8; j++) {
                float sq  = xr[j] * xr[j];
                float s16 = __shfl_xor(sq, 16, 64);
                float s32 = __shfl_xor(sq, 32, 64);
                float s48 = __shfl_xor(sq, 48, 64);
                pr[j] = ((sq + s16) + s32) + s48;   // canonical on lanes 0..15 (= token id)
            }
            float x2tok = ((pr[0] + pr[1]) + (pr[2] + pr[3])) + ((pr[4] + pr[5]) + (pr[6] + pr[7]));
#pragma unroll
            for (int r = 0; r < 4; r++)
                x2b[r] = __shfl(x2tok, q * 4 + r, 64);   // x2 of this lane's C-row tokens
        }

        // ---- 16 MFMA tiles: approx scores s = c2 - 2*x.c for all 256 codes ----
        const f32x4 accz = {0.f, 0.f, 0.f, 0.f};
        float sc[16][4];
        float minv4[4] = {FINF, FINF, FINF, FINF};
#pragma unroll
        for (int t = 0; t < 16; t++) {
            bf16x8 bfr = *(const bf16x8*)&cbb[(t * 16 + m) * 40 + q * 8];
            float  c2v = c2s[t * 16 + m];
            f32x4  acc = __builtin_amdgcn_mfma_f32_16x16x32_bf16(af, bfr, accz, 0, 0, 0);
#pragma unroll
            for (int r = 0; r < 4; r++) {
                float s = fmaf(-2.f, acc[r], c2v);
                sc[t][r] = s;
                minv4[r] = fminf(minv4[r], s);
            }
        }
#pragma unroll
        for (int mm = 1; mm < 16; mm <<= 1)
#pragma unroll
            for (int r = 0; r < 4; r++)
                minv4[r] = fminf(minv4[r], __shfl_xor(minv4[r], mm, 64));

        // ---- candidates within margin: exact np-order f32 rescore ----
        float bestE[4] = {FINF, FINF, FINF, FINF};
        int   bestI[4] = {0x7fffffff, 0x7fffffff, 0x7fffffff, 0x7fffffff};
#pragma unroll
        for (int t = 0; t < 16; t++) {
#pragma unroll
            for (int r = 0; r < 4; r++) {
                if (sc[t][r] <= minv4[r] + DELTA) {
                    const int    code = t * 16 + m;
                    const size_t tok  = (size_t)t0 + q * 4 + r;
                    const float4* xp = (const float4*)(x + tok * D);
                    const float4* cp = (const float4*)(cb + (size_t)code * D);
                    float acc = 0.f;
#pragma unroll
                    for (int c = 0; c < 8; c++) {       // sequential fmaf, k ascending
                        float4 a = xp[c], b = cp[c];
                        acc = fmaf(a.x, b.x, acc);
                        acc = fmaf(a.y, b.y, acc);
                        acc = fmaf(a.z, b.z, acc);
                        acc = fmaf(a.w, b.w, acc);
                    }
                    float t2 = x2b[r] - 2.0f * acc;     // 2*acc exact; single rounding
                    float s2 = t2 + c2s[code];          // fl(fl(x2-2xc)+c2) == np
                    if (s2 < bestE[r] || (s2 == bestE[r] && code < bestI[r])) {
                        bestE[r] = s2; bestI[r] = code;
                    }
                }
            }
        }
        // cross-lane exact argmin (16 code-lanes per token group), lowest-index tie-break
#pragma unroll
        for (int mm = 1; mm < 16; mm <<= 1)
#pragma unroll
            for (int r = 0; r < 4; r++) {
                float ov = __shfl_xor(bestE[r], mm, 64);
                int   oi = __shfl_xor(bestI[r], mm, 64);
                if (ov < bestE[r] || (ov == bestE[r] && oi < bestI[r])) {
                    bestE[r] = ov; bestI[r] = oi;
                }
            }

        // ---- rotation: lane L -> token L>>2 (in lane's own reduce-group), sub = L&3 ----
        {
            const int tl  = lane >> 2;
            const int sub = lane & 3;
            const int r   = tl & 3;
            int bi = (r == 0) ? bestI[0] : (r == 1) ? bestI[1] : (r == 2) ? bestI[2] : bestI[3];
            const size_t gtok = (size_t)t0 + tl;

            const float4* xg = (const float4*)(x + gtok * D + sub * 8);
            float4 xa = xg[0], xb = xg[1];
            const float4* cg = (const float4*)(cb + (size_t)bi * D + sub * 8);
            float4 ca = cg[0], cbv = cg[1];

            float xs8[8] = {xa.x, xa.y, xa.z, xa.w, xb.x, xb.y, xb.z, xb.w};
            float cs8[8] = {ca.x, ca.y, ca.z, ca.w, cbv.x, cbv.y, cbv.z, cbv.w};

            float px2 = 0.f, pc2 = 0.f;
#pragma unroll
            for (int j = 0; j < 8; j++) { px2 = fmaf(xs8[j], xs8[j], px2); pc2 = fmaf(cs8[j], cs8[j], pc2); }
            float x2 = px2 + __shfl_xor(px2, 1, 64); x2 += __shfl_xor(x2, 2, 64);
            float c2 = pc2 + __shfl_xor(pc2, 1, 64); c2 += __shfl_xor(c2, 2, 64);
            const float inx = 1.f / fmaxf(sqrtf(x2), EPSF);
            const float inc = 1.f / fmaxf(sqrtf(c2), EPSF);

            float us8[8], qs8[8], ws8[8];
            float pw2 = 0.f;
#pragma unroll
            for (int j = 0; j < 8; j++) {
                us8[j] = xs8[j] * inx;
                qs8[j] = cs8[j] * inc;
                ws8[j] = us8[j] + qs8[j];
                pw2 = fmaf(ws8[j], ws8[j], pw2);
            }
            float w2 = pw2 + __shfl_xor(pw2, 1, 64); w2 += __shfl_xor(w2, 2, 64);
            const float inw = 1.f / fmaxf(sqrtf(w2), EPSF);

            float pew = 0.f, peu = 0.f;
#pragma unroll
            for (int j = 0; j < 8; j++) {
                ws8[j] *= inw;
                pew = fmaf(xs8[j], ws8[j], pew);
                peu = fmaf(xs8[j], us8[j], peu);
            }
            float ew = pew + __shfl_xor(pew, 1, 64); ew += __shfl_xor(ew, 2, 64);
            float eu = peu + __shfl_xor(peu, 1, 64); eu += __shfl_xor(eu, 2, 64);

            float ro[8];
#pragma unroll
            for (int j = 0; j < 8; j++)
                ro[j] = xs8[j] - 2.f * ew * ws8[j] + 2.f * eu * qs8[j];

            float4* og = (float4*)(out_rot + gtok * D + sub * 8);
            og[0] = make_float4(ro[0], ro[1], ro[2], ro[3]);
            og[1] = make_float4(ro[4], ro[5], ro[6], ro[7]);

            if (sub == 0) {
                out_idx[gtok] = (float)bi;
                atomicAdd(&hist[bi], 1.f);
            }
        }
    }

    __syncthreads();
    if (use_ws) ws[WS_HIST_OFF + (size_t)blockIdx.x * KC + tid] = hist[tid];
    else        atomicAdd(&out_cnt[tid], hist[tid]);
}

// ---------------- tiny reduce: block-partials -> 256 counts ----------------
__global__ __launch_bounds__(256) void vq_reduce(const float* __restrict__ ws,
                                                 float* __restrict__ out_cnt)
{
    const int c = blockIdx.x * 8 + (threadIdx.x >> 5);
    const int l = threadIdx.x & 31;
    float s = 0.f;
    for (int b = l; b < NBLK; b += 32) s += ws[WS_HIST_OFF + (size_t)b * KC + c];
#pragma unroll
    for (int mm = 1; mm < 32; mm <<= 1) s += __shfl_xor(s, mm, 64);
    if (l == 0) out_cnt[c] = s;
}

extern "C" void kernel_launch(void* const* d_in, const int* in_sizes, int n_in,
                              void* d_out, int out_size, void* d_ws, size_t ws_size,
                              hipStream_t stream)
{
    const float* x  = (const float*)d_in[0];
    const float* cb = (const float*)d_in[1];
    float* out      = (float*)d_out;
    float* out_rot  = out;
    float* out_idx  = out + (size_t)N_TOK * D;
    float* out_cnt  = out_idx + N_TOK;

    const size_t ws_need = (WS_HIST_OFF + (size_t)NBLK * KC) * sizeof(float);
    const int use_ws = (ws_size >= ws_need) ? 1 : 0;
    if (use_ws) {
        hipMemsetAsync(d_ws, 0, WS_HIST_OFF * sizeof(float), stream);
    } else {
        hipMemsetAsync(out_cnt, 0, KC * sizeof(float), stream);
    }

    vq_main<<<NBLK, BLKT, 0, stream>>>(x, cb, out_rot, out_idx,
                                       (float*)d_ws, out_cnt, use_ws);
    if (use_ws) vq_reduce<<<32, 256, 0, stream>>>((const float*)d_ws, out_cnt);
}